// Round 7
// baseline (248.845 us; speedup 1.0000x reference)
//
#include <hip/hip_runtime.h>
#include <hip/hip_bf16.h>

#define S_LEN 2048
#define DH    64
#define NBH   32          // B*H
#define KVT   32          // keys per tile
#define NT    64          // tiles per bh (S/KVT)

typedef __attribute__((ext_vector_type(8)))  short short8;
typedef __attribute__((ext_vector_type(4)))  float f32x4;
typedef __attribute__((ext_vector_type(16))) float f32x16;

static __device__ __forceinline__ unsigned cvtpk_bf16(float a, float b) {
    unsigned r;
    asm("v_cvt_pk_bf16_f32 %0, %1, %2" : "=v"(r) : "v"(a), "v"(b));
    return r;
}
// cross-half (lane ^ 32) reductions — __shfl_xor is proven on this target.
// (permlane32_swap with two identical "+v" operands gets register-coalesced
//  into a self-swap, dropping each lane's own half. Do not reintroduce.)
static __device__ __forceinline__ float xor32_max(float x) {
    return fmaxf(x, __shfl_xor(x, 32));
}
static __device__ __forceinline__ float xor32_add(float x) {
    return x + __shfl_xor(x, 32);
}

// ---------------------------------------------------------------------------
// prep: K,V fp32 -> bf16 fragment images (4 KB per 32-key tile).
// Kimg tile: [key 0..31][128B = 64 d bf16]   (MFMA A-operand rows)
// Vimg tile: [d 0..63][64B = 32 keys bf16]   (V^T, PV A-operand rows)
// grid = (NT, NBH), 256 threads.
// ---------------------------------------------------------------------------
__global__ __launch_bounds__(256)
void prep_kernel(const float* __restrict__ K, const float* __restrict__ V,
                 char* __restrict__ Kimg, char* __restrict__ Vimg)
{
    const int t = blockIdx.x, bh = blockIdx.y, tid = threadIdx.x;
    const long tileOff = ((long)bh * NT + t) * 4096;
    const float* kp = K + (long)bh * S_LEN * DH + t * KVT * DH;
    const float* vp = V + (long)bh * S_LEN * DH + t * KVT * DH;

    {   // K rows
        int key = tid >> 3, dc = tid & 7;
        f32x4 x = *(const f32x4*)(kp + key * 64 + dc * 8);
        f32x4 y = *(const f32x4*)(kp + key * 64 + dc * 8 + 4);
        uint4 w;
        w.x = cvtpk_bf16(x[0], x[1]);
        w.y = cvtpk_bf16(x[2], x[3]);
        w.z = cvtpk_bf16(y[0], y[1]);
        w.w = cvtpk_bf16(y[2], y[3]);
        *(uint4*)(Kimg + tileOff + key * 128 + dc * 16) = w;
    }
    {   // V^T rows: thread -> (d = tid>>2, key-chunk c = tid&3), 16B store
        int d = tid >> 2, c = tid & 3;
        int k0 = c * 8;
        uint4 w;
        #pragma unroll
        for (int p = 0; p < 4; ++p) {
            float a = vp[(k0 + 2 * p) * 64 + d];
            float b = vp[(k0 + 2 * p + 1) * 64 + d];
            ((unsigned*)&w)[p] = cvtpk_bf16(a, b);
        }
        *(uint4*)(Vimg + tileOff + d * 64 + k0 * 2) = w;
    }
}

// ---------------------------------------------------------------------------
// pre: fz[b] = first k with pad==0 (S if none); bias[b][k] = pad?-1e30:0;
// zero the 8 XCD work-queue counters. grid = 2 blocks (one per batch).
// ---------------------------------------------------------------------------
__global__ __launch_bounds__(256)
void pre_kernel(const int* __restrict__ pad, int* __restrict__ fz,
                float* __restrict__ bias, int* __restrict__ qctr)
{
    const int b = blockIdx.x, tid = threadIdx.x;
    if (b == 0 && tid < 8) qctr[tid] = 0;
    __shared__ int ired[256];
    int local = S_LEN;
    for (int k = tid; k < S_LEN; k += 256) {
        int pv = pad[b * S_LEN + k];
        if (pv == 0 && k < local) local = k;
        bias[b * S_LEN + k] = pv ? -1e30f : 0.f;
    }
    ired[tid] = local;
    __syncthreads();
    for (int s = 128; s > 0; s >>= 1) {
        if (tid < s) ired[tid] = min(ired[tid], ired[tid + s]);
        __syncthreads();
    }
    if (tid == 0) fz[b] = ired[0];
}

// ---------------------------------------------------------------------------
// meanv[bh][d] = mean over 2048 keys of V[bh,:,d] (only if fz[b] > 0).
// 1024 threads (round-4 proven-fast version).
// ---------------------------------------------------------------------------
__global__ __launch_bounds__(1024)
void meanv_kernel(const float* __restrict__ V, const int* __restrict__ fz,
                  float* __restrict__ meanv)
{
    const int bh = blockIdx.x;
    const int b  = bh >> 4;
    if (fz[b] <= 0) return;
    const int d4 = threadIdx.x & 15;
    const int kp = threadIdx.x >> 4;
    const float* vp = V + (long)bh * S_LEN * DH;
    f32x4 acc = (f32x4){0.f, 0.f, 0.f, 0.f};
    #pragma unroll 4
    for (int k = kp; k < S_LEN; k += 64)
        acc += *(const f32x4*)(vp + (long)k * DH + d4 * 4);
    __shared__ f32x4 red[64][16];
    red[kp][d4] = acc;
    __syncthreads();
    #pragma unroll
    for (int s = 32; s >= 1; s >>= 1) {
        if (kp < s) red[kp][d4] += red[kp + s][d4];
        __syncthreads();
    }
    if (kp == 0)
        *(f32x4*)(meanv + bh * DH + d4 * 4) = red[0][d4] * (1.0f / 2048.0f);
}

// ---------------------------------------------------------------------------
// attn v4: persistent 1-wave blocks + 8 XCD-local atomic work queues.
// Queue q holds 256 items: j -> bh = q + 8*(j&3), bx = 63 - (j>>2)  (heavy
// first). All waves on XCD q touch only 4 bh's -> 2 MB of images, L2-resident.
// Coverage is placement-independent: each wave sweeps all 8 queues, so every
// item is processed even under arbitrary block->XCD assignment (G16).
// ---------------------------------------------------------------------------
#define LOADK(dst, tt) do { const char* _p = KB + (long)(tt) * 4096 + lq * 128 + hi * 16; \
    dst[0] = *(const short8*)(_p);       dst[1] = *(const short8*)(_p + 32);  \
    dst[2] = *(const short8*)(_p + 64);  dst[3] = *(const short8*)(_p + 96); } while (0)
#define LOADV(dst, tt) do { const char* _p = VB + (long)(tt) * 4096 + lq * 64 + hi * 16; \
    dst[0] = *(const short8*)(_p);        dst[1] = *(const short8*)(_p + 32); \
    dst[2] = *(const short8*)(_p + 2048); dst[3] = *(const short8*)(_p + 2048 + 32); } while (0)
#define LOADB(dst, tt) do { const float* _p = biasB + (tt) * 32 + hi * 4; \
    dst[0] = *(const f32x4*)(_p);      dst[1] = *(const f32x4*)(_p + 8); \
    dst[2] = *(const f32x4*)(_p + 16); dst[3] = *(const f32x4*)(_p + 24); } while (0)

#define COMPUTE(TT, K_, V_, B_) do {                                          \
    f32x16 s0;                                                                \
    _Pragma("unroll")                                                         \
    for (int g = 0; g < 4; ++g) {                                             \
        f32x4 pb4 = B_[g];                                                    \
        _Pragma("unroll")                                                     \
        for (int i = 0; i < 4; ++i) s0[g * 4 + i] = pb4[i];                   \
    }                                                                         \
    __builtin_amdgcn_s_setprio(1);                                            \
    s0 = __builtin_amdgcn_mfma_f32_32x32x16_bf16(K_[0], bq[0], s0, 0, 0, 0);  \
    s0 = __builtin_amdgcn_mfma_f32_32x32x16_bf16(K_[1], bq[1], s0, 0, 0, 0);  \
    s0 = __builtin_amdgcn_mfma_f32_32x32x16_bf16(K_[2], bq[2], s0, 0, 0, 0);  \
    s0 = __builtin_amdgcn_mfma_f32_32x32x16_bf16(K_[3], bq[3], s0, 0, 0, 0);  \
    __builtin_amdgcn_s_setprio(0);                                            \
    if ((TT) == nkv - 1) {                                                    \
        _Pragma("unroll")                                                     \
        for (int rr = 0; rr < 16; ++rr) {                                     \
            int key_r = (rr & 3) + 8 * (rr >> 2) + 4 * hi;                    \
            if (key_r > lq) s0[rr] = -1e30f;                                  \
        }                                                                     \
    }                                                                         \
    float bm = s0[0];                                                         \
    _Pragma("unroll")                                                         \
    for (int rr = 1; rr < 16; ++rr) bm = fmaxf(bm, s0[rr]);                   \
    bm = xor32_max(bm);                                                       \
    if (__any(bm > m_run + 8.0f)) {                                           \
        float mnew = fmaxf(m_run, bm);                                        \
        float c = exp2f(m_run - mnew);                                        \
        m_run = mnew; l_run *= c;                                             \
        _Pragma("unroll")                                                     \
        for (int rr = 0; rr < 16; ++rr) { o0[rr] *= c; o1[rr] *= c; }         \
    }                                                                         \
    float rs = 0.f;                                                           \
    _Pragma("unroll")                                                         \
    for (int rr = 0; rr < 16; ++rr) {                                         \
        float p = exp2f(s0[rr] - m_run);                                      \
        s0[rr] = p; rs += p;                                                  \
    }                                                                         \
    l_run += xor32_add(rs);                                                   \
    short8 pfr0, pfr1;                                                        \
    {                                                                         \
        unsigned a0 = cvtpk_bf16(s0[0], s0[1]), b0 = cvtpk_bf16(s0[4], s0[5]);\
        asm("v_permlane32_swap_b32 %0, %1" : "+v"(a0), "+v"(b0));             \
        unsigned a1 = cvtpk_bf16(s0[2], s0[3]), b1 = cvtpk_bf16(s0[6], s0[7]);\
        asm("v_permlane32_swap_b32 %0, %1" : "+v"(a1), "+v"(b1));             \
        union { short8 s8; unsigned u[4]; } u;                                \
        u.u[0] = a0; u.u[1] = a1; u.u[2] = b0; u.u[3] = b1;                   \
        pfr0 = u.s8;                                                          \
    }                                                                         \
    {                                                                         \
        unsigned a0 = cvtpk_bf16(s0[8], s0[9]),  b0 = cvtpk_bf16(s0[12], s0[13]); \
        asm("v_permlane32_swap_b32 %0, %1" : "+v"(a0), "+v"(b0));             \
        unsigned a1 = cvtpk_bf16(s0[10], s0[11]), b1 = cvtpk_bf16(s0[14], s0[15]); \
        asm("v_permlane32_swap_b32 %0, %1" : "+v"(a1), "+v"(b1));             \
        union { short8 s8; unsigned u[4]; } u;                                \
        u.u[0] = a0; u.u[1] = a1; u.u[2] = b0; u.u[3] = b1;                   \
        pfr1 = u.s8;                                                          \
    }                                                                         \
    __builtin_amdgcn_s_setprio(1);                                            \
    o0 = __builtin_amdgcn_mfma_f32_32x32x16_bf16(V_[0], pfr0, o0, 0, 0, 0);   \
    o0 = __builtin_amdgcn_mfma_f32_32x32x16_bf16(V_[1], pfr1, o0, 0, 0, 0);   \
    o1 = __builtin_amdgcn_mfma_f32_32x32x16_bf16(V_[2], pfr0, o1, 0, 0, 0);   \
    o1 = __builtin_amdgcn_mfma_f32_32x32x16_bf16(V_[3], pfr1, o1, 0, 0, 0);   \
    __builtin_amdgcn_s_setprio(0);                                            \
} while (0)

__global__ __launch_bounds__(64, 2)
void attn_fwd4(const float* __restrict__ Q, const char* __restrict__ Kimg,
               const char* __restrict__ Vimg, const float* __restrict__ bias,
               float* __restrict__ out, int* __restrict__ qctr)
{
    const int lane = threadIdx.x;
    const int lq = lane & 31, hi = lane >> 5;

    int xcd;
    asm volatile("s_getreg_b32 %0, hwreg(HW_REG_XCC_ID)" : "=s"(xcd));
    xcd &= 7;

    const float QS = 0.18033688011112042f;   // (1/8)*log2(e)

    for (int qi = 0; qi < 8; ++qi) {
        const int q = (xcd + qi) & 7;
        for (;;) {
            int j0 = 0;
            if (lane == 0) j0 = atomicAdd(qctr + q, 1);
            const int j = __shfl(j0, 0);
            if (j >= 256) break;

            const int bh  = q + 8 * (j & 3);
            const int bx  = 63 - (j >> 2);
            const int q0  = bx * 32;
            const int nkv = bx + 1;
            const long base = (long)bh * S_LEN * DH;

            const char*  KB    = Kimg + (long)bh * NT * 4096;
            const char*  VB    = Vimg + (long)bh * NT * 4096;
            const float* biasB = bias + (bh >> 4) * S_LEN;

            // Q fragments (B operand), scale folded
            short8 bq[4];
            {
                const float* qp = Q + base + (long)(q0 + lq) * DH;
                #pragma unroll
                for (int s = 0; s < 4; ++s) {
                    int d0 = s * 16 + hi * 8;
                    f32x4 x = *(const f32x4*)(qp + d0);
                    f32x4 y = *(const f32x4*)(qp + d0 + 4);
                    union { short8 s8; unsigned u[4]; } u;
                    u.u[0] = cvtpk_bf16(x[0] * QS, x[1] * QS);
                    u.u[1] = cvtpk_bf16(x[2] * QS, x[3] * QS);
                    u.u[2] = cvtpk_bf16(y[0] * QS, y[1] * QS);
                    u.u[3] = cvtpk_bf16(y[2] * QS, y[3] * QS);
                    bq[s] = u.s8;
                }
            }

            f32x16 o0, o1;
            #pragma unroll
            for (int rr = 0; rr < 16; ++rr) { o0[rr] = 0.f; o1[rr] = 0.f; }
            float m_run = -1e30f, l_run = 0.f;

            short8 ka[4], kb_[4], va[4], vb_[4];
            f32x4  ba[4], bb[4];

            LOADB(ba, 0); LOADK(ka, 0); LOADV(va, 0);
            int t = 0;
            for (;;) {
                if (t + 1 < nkv) { LOADB(bb, t + 1); LOADK(kb_, t + 1); LOADV(vb_, t + 1); }
                COMPUTE(t, ka, va, ba);
                ++t; if (t >= nkv) break;
                if (t + 1 < nkv) { LOADB(ba, t + 1); LOADK(ka, t + 1); LOADV(va, t + 1); }
                COMPUTE(t, kb_, vb_, bb);
                ++t; if (t >= nkv) break;
            }

            // epilogue: out[q0+lq][d], d over o0 (0..31) / o1 (32..63)
            float invl = 1.0f / l_run;
            float* op = out + base + (long)(q0 + lq) * DH;
            #pragma unroll
            for (int g = 0; g < 4; ++g) {
                f32x4 w0, w1;
                #pragma unroll
                for (int i = 0; i < 4; ++i) {
                    w0[i] = o0[g * 4 + i] * invl;
                    w1[i] = o1[g * 4 + i] * invl;
                }
                *(f32x4*)(op + g * 8 + hi * 4)      = w0;
                *(f32x4*)(op + 32 + g * 8 + hi * 4) = w1;
            }
        }
    }
}

// ---------------------------------------------------------------------------
// Rows q < fz[b]: reference softmax degenerates to uniform over ALL 2048 keys
// (scores all exactly -1e9 in fp32) -> out = mean(V). Overwrite them.
// ---------------------------------------------------------------------------
__global__ void fixup_kernel(const int* __restrict__ fz, const float* __restrict__ meanv,
                             float* __restrict__ out)
{
    const int bh = blockIdx.x;
    const int b  = bh >> 4;
    const int n  = fz[b];
    if (n <= 0) return;
    __shared__ float mv[DH];
    if (threadIdx.x < DH) mv[threadIdx.x] = meanv[bh * DH + threadIdx.x];
    __syncthreads();
    float* op = out + (long)bh * S_LEN * DH;
    for (int i = threadIdx.x; i < n * DH; i += 256) op[i] = mv[i & 63];
}

extern "C" void kernel_launch(void* const* d_in, const int* in_sizes, int n_in,
                              void* d_out, int out_size, void* d_ws, size_t ws_size,
                              hipStream_t stream)
{
    const float* Q   = (const float*)d_in[0];
    const float* K   = (const float*)d_in[1];
    const float* V   = (const float*)d_in[2];
    const int*   pad = (const int*)d_in[3];
    float* out = (float*)d_out;

    int*   qctr  = (int*)d_ws;                          // 8 ints
    int*   fz    = (int*)((char*)d_ws + 256);           // 2 ints
    float* meanv = (float*)((char*)d_ws + 512);         // 32*64 f32
    float* bias  = (float*)((char*)d_ws + 12288);       // 2*2048 f32
    char*  Kimg  = (char*)d_ws + 32768;                 // 8 MB
    char*  Vimg  = Kimg + (size_t)NBH * NT * 4096;      // 8 MB

    pre_kernel<<<dim3(2), dim3(256), 0, stream>>>(pad, fz, bias, qctr);
    prep_kernel<<<dim3(NT, NBH), dim3(256), 0, stream>>>(K, V, Kimg, Vimg);
    attn_fwd4<<<dim3(2048), dim3(64), 0, stream>>>(Q, Kimg, Vimg, bias, out, qctr);
    meanv_kernel<<<dim3(NBH), dim3(1024), 0, stream>>>(V, fz, meanv);
    fixup_kernel<<<dim3(NBH), dim3(256), 0, stream>>>(fz, meanv, out);
}

// Round 8
// 117.151 us; speedup vs baseline: 2.1241x; 2.1241x over previous
//
#include <hip/hip_runtime.h>
#include <hip/hip_bf16.h>

#define S_LEN 2048
#define DH    64
#define NBH   32          // B*H
#define KVT   32          // keys per tile
#define NT    64          // tiles per bh (S/KVT)

typedef __attribute__((ext_vector_type(8)))  short short8;
typedef __attribute__((ext_vector_type(4)))  float f32x4;
typedef __attribute__((ext_vector_type(16))) float f32x16;

static __device__ __forceinline__ unsigned cvtpk_bf16(float a, float b) {
    unsigned r;
    asm("v_cvt_pk_bf16_f32 %0, %1, %2" : "=v"(r) : "v"(a), "v"(b));
    return r;
}
// cross-half (lane ^ 32) reductions — __shfl_xor is proven on this target.
// (permlane32_swap with two identical "+v" operands gets register-coalesced
//  into a self-swap, dropping each lane's own half. Do not reintroduce.)
static __device__ __forceinline__ float xor32_max(float x) {
    return fmaxf(x, __shfl_xor(x, 32));
}
static __device__ __forceinline__ float xor32_add(float x) {
    return x + __shfl_xor(x, 32);
}

// ---------------------------------------------------------------------------
// prep: K,V fp32 -> bf16 fragment images (4 KB per 32-key tile).
// Kimg tile: [key 0..31][128B = 64 d bf16]   (MFMA A-operand rows)
// Vimg tile: [d 0..63][64B = 32 keys bf16]   (V^T, PV A-operand rows)
// grid = (NT, NBH), 256 threads.
// ---------------------------------------------------------------------------
__global__ __launch_bounds__(256)
void prep_kernel(const float* __restrict__ K, const float* __restrict__ V,
                 char* __restrict__ Kimg, char* __restrict__ Vimg)
{
    const int t = blockIdx.x, bh = blockIdx.y, tid = threadIdx.x;
    const long tileOff = ((long)bh * NT + t) * 4096;
    const float* kp = K + (long)bh * S_LEN * DH + t * KVT * DH;
    const float* vp = V + (long)bh * S_LEN * DH + t * KVT * DH;

    {   // K rows
        int key = tid >> 3, dc = tid & 7;
        f32x4 x = *(const f32x4*)(kp + key * 64 + dc * 8);
        f32x4 y = *(const f32x4*)(kp + key * 64 + dc * 8 + 4);
        uint4 w;
        w.x = cvtpk_bf16(x[0], x[1]);
        w.y = cvtpk_bf16(x[2], x[3]);
        w.z = cvtpk_bf16(y[0], y[1]);
        w.w = cvtpk_bf16(y[2], y[3]);
        *(uint4*)(Kimg + tileOff + key * 128 + dc * 16) = w;
    }
    {   // V^T rows (4x2 micro-transpose per thread)
        int vdg = tid & 15, vkq = tid >> 4;
        int d0 = vdg * 4, k0 = vkq * 2;
        f32x4 x0 = *(const f32x4*)(vp + k0 * 64 + d0);
        f32x4 x1 = *(const f32x4*)(vp + (k0 + 1) * 64 + d0);
        #pragma unroll
        for (int i = 0; i < 4; ++i)
            *(unsigned*)(Vimg + tileOff + (d0 + i) * 64 + k0 * 2) = cvtpk_bf16(x0[i], x1[i]);
    }
}

// ---------------------------------------------------------------------------
// fz[b] = first k with pad==0 (S if none)
// ---------------------------------------------------------------------------
__global__ void fz_kernel(const int* __restrict__ pad, int* __restrict__ fz)
{
    int b = blockIdx.x;
    __shared__ int red[256];
    int local = S_LEN;
    for (int k = threadIdx.x; k < S_LEN; k += 256)
        if (pad[b * S_LEN + k] == 0 && k < local) local = k;
    red[threadIdx.x] = local;
    __syncthreads();
    for (int s = 128; s > 0; s >>= 1) {
        if (threadIdx.x < s) red[threadIdx.x] = min(red[threadIdx.x], red[threadIdx.x + s]);
        __syncthreads();
    }
    if (threadIdx.x == 0) fz[b] = red[0];
}

// bias[b][k] = pad ? -1e30 : 0
__global__ __launch_bounds__(1024)
void bias_kernel(const int* __restrict__ pad, float* __restrict__ bias)
{
    int b = blockIdx.x;
    #pragma unroll
    for (int i = 0; i < 2; ++i) {
        int k = threadIdx.x + i * 1024;
        bias[b * S_LEN + k] = pad[b * S_LEN + k] ? -1e30f : 0.f;
    }
}

// ---------------------------------------------------------------------------
// meanv[bh][d] = mean over 2048 keys of V[bh,:,d] (only if fz[b] > 0).
// ---------------------------------------------------------------------------
__global__ __launch_bounds__(1024)
void meanv_kernel(const float* __restrict__ V, const int* __restrict__ fz,
                  float* __restrict__ meanv)
{
    const int bh = blockIdx.x;
    const int b  = bh >> 4;
    if (fz[b] <= 0) return;
    const int d4 = threadIdx.x & 15;
    const int kp = threadIdx.x >> 4;
    const float* vp = V + (long)bh * S_LEN * DH;
    f32x4 acc = (f32x4){0.f, 0.f, 0.f, 0.f};
    #pragma unroll 4
    for (int k = kp; k < S_LEN; k += 64)
        acc += *(const f32x4*)(vp + (long)k * DH + d4 * 4);
    __shared__ f32x4 red[64][16];
    red[kp][d4] = acc;
    __syncthreads();
    #pragma unroll
    for (int s = 32; s >= 1; s >>= 1) {
        if (kp < s) red[kp][d4] += red[kp + s][d4];
        __syncthreads();
    }
    if (kp == 0)
        *(f32x4*)(meanv + bh * DH + d4 * 4) = red[0][d4] * (1.0f / 2048.0f);
}

// ---------------------------------------------------------------------------
// attn v5: 1-wave blocks, zero LDS, zero barriers, STATIC interleaved-
// complementary XCD-class mapping:
//   x = gid&7 (presumed XCD under round-robin dispatch), u = gid>>3:
//   bh = x + 8*(u&3)            -> each class touches only 4 bh (2 MB, L2-fit)
//   w = u>>2, bx = (w&1) ? w>>1 : 63-(w>>1)
//                               -> launch-adjacent blocks alternate heavy/light
// Pure performance heuristic: any placement still gives full coverage (G16).
// ---------------------------------------------------------------------------
#define LOADK(dst, tt) do { const char* _p = KB + (long)(tt) * 4096 + lq * 128 + hi * 16; \
    dst[0] = *(const short8*)(_p);       dst[1] = *(const short8*)(_p + 32);  \
    dst[2] = *(const short8*)(_p + 64);  dst[3] = *(const short8*)(_p + 96); } while (0)
#define LOADV(dst, tt) do { const char* _p = VB + (long)(tt) * 4096 + lq * 64 + hi * 16; \
    dst[0] = *(const short8*)(_p);        dst[1] = *(const short8*)(_p + 32); \
    dst[2] = *(const short8*)(_p + 2048); dst[3] = *(const short8*)(_p + 2048 + 32); } while (0)
#define LOADB(dst, tt) do { const float* _p = biasB + (tt) * 32 + hi * 4; \
    dst[0] = *(const f32x4*)(_p);      dst[1] = *(const f32x4*)(_p + 8); \
    dst[2] = *(const f32x4*)(_p + 16); dst[3] = *(const f32x4*)(_p + 24); } while (0)

#define COMPUTE(TT, K_, V_, B_) do {                                          \
    f32x16 s0;                                                                \
    _Pragma("unroll")                                                         \
    for (int g = 0; g < 4; ++g) {                                             \
        f32x4 pb4 = B_[g];                                                    \
        _Pragma("unroll")                                                     \
        for (int i = 0; i < 4; ++i) s0[g * 4 + i] = pb4[i];                   \
    }                                                                         \
    __builtin_amdgcn_s_setprio(1);                                            \
    s0 = __builtin_amdgcn_mfma_f32_32x32x16_bf16(K_[0], bq[0], s0, 0, 0, 0);  \
    s0 = __builtin_amdgcn_mfma_f32_32x32x16_bf16(K_[1], bq[1], s0, 0, 0, 0);  \
    s0 = __builtin_amdgcn_mfma_f32_32x32x16_bf16(K_[2], bq[2], s0, 0, 0, 0);  \
    s0 = __builtin_amdgcn_mfma_f32_32x32x16_bf16(K_[3], bq[3], s0, 0, 0, 0);  \
    __builtin_amdgcn_s_setprio(0);                                            \
    if ((TT) == nkv - 1) {                                                    \
        _Pragma("unroll")                                                     \
        for (int rr = 0; rr < 16; ++rr) {                                     \
            int key_r = (rr & 3) + 8 * (rr >> 2) + 4 * hi;                    \
            if (key_r > lq) s0[rr] = -1e30f;                                  \
        }                                                                     \
    }                                                                         \
    float bm = s0[0];                                                         \
    _Pragma("unroll")                                                         \
    for (int rr = 1; rr < 16; ++rr) bm = fmaxf(bm, s0[rr]);                   \
    bm = xor32_max(bm);                                                       \
    if (__any(bm > m_run + 8.0f)) {                                           \
        float mnew = fmaxf(m_run, bm);                                        \
        float c = exp2f(m_run - mnew);                                        \
        m_run = mnew; l_run *= c;                                             \
        _Pragma("unroll")                                                     \
        for (int rr = 0; rr < 16; ++rr) { o0[rr] *= c; o1[rr] *= c; }         \
    }                                                                         \
    float rs = 0.f;                                                           \
    _Pragma("unroll")                                                         \
    for (int rr = 0; rr < 16; ++rr) {                                         \
        float p = exp2f(s0[rr] - m_run);                                      \
        s0[rr] = p; rs += p;                                                  \
    }                                                                         \
    l_run += xor32_add(rs);                                                   \
    short8 pfr0, pfr1;                                                        \
    {                                                                         \
        unsigned a0 = cvtpk_bf16(s0[0], s0[1]), b0 = cvtpk_bf16(s0[4], s0[5]);\
        asm("v_permlane32_swap_b32 %0, %1" : "+v"(a0), "+v"(b0));             \
        unsigned a1 = cvtpk_bf16(s0[2], s0[3]), b1 = cvtpk_bf16(s0[6], s0[7]);\
        asm("v_permlane32_swap_b32 %0, %1" : "+v"(a1), "+v"(b1));             \
        union { short8 s8; unsigned u[4]; } u;                                \
        u.u[0] = a0; u.u[1] = a1; u.u[2] = b0; u.u[3] = b1;                   \
        pfr0 = u.s8;                                                          \
    }                                                                         \
    {                                                                         \
        unsigned a0 = cvtpk_bf16(s0[8], s0[9]),  b0 = cvtpk_bf16(s0[12], s0[13]); \
        asm("v_permlane32_swap_b32 %0, %1" : "+v"(a0), "+v"(b0));             \
        unsigned a1 = cvtpk_bf16(s0[10], s0[11]), b1 = cvtpk_bf16(s0[14], s0[15]); \
        asm("v_permlane32_swap_b32 %0, %1" : "+v"(a1), "+v"(b1));             \
        union { short8 s8; unsigned u[4]; } u;                                \
        u.u[0] = a0; u.u[1] = a1; u.u[2] = b0; u.u[3] = b1;                   \
        pfr1 = u.s8;                                                          \
    }                                                                         \
    __builtin_amdgcn_s_setprio(1);                                            \
    o0 = __builtin_amdgcn_mfma_f32_32x32x16_bf16(V_[0], pfr0, o0, 0, 0, 0);   \
    o0 = __builtin_amdgcn_mfma_f32_32x32x16_bf16(V_[1], pfr1, o0, 0, 0, 0);   \
    o1 = __builtin_amdgcn_mfma_f32_32x32x16_bf16(V_[2], pfr0, o1, 0, 0, 0);   \
    o1 = __builtin_amdgcn_mfma_f32_32x32x16_bf16(V_[3], pfr1, o1, 0, 0, 0);   \
    __builtin_amdgcn_s_setprio(0);                                            \
} while (0)

__global__ __launch_bounds__(64, 2)
void attn_fwd5(const float* __restrict__ Q, const char* __restrict__ Kimg,
               const char* __restrict__ Vimg, const float* __restrict__ bias,
               float* __restrict__ out)
{
    const int lane = threadIdx.x;
    const int lq = lane & 31, hi = lane >> 5;

    const int gid = blockIdx.x;
    const int x   = gid & 7;
    const int u   = gid >> 3;            // 0..255
    const int bh  = x + 8 * (u & 3);
    const int w   = u >> 2;              // 0..63
    const int bx  = (w & 1) ? (w >> 1) : 63 - (w >> 1);
    const int q0  = bx * 32;
    const int nkv = bx + 1;
    const long base = (long)bh * S_LEN * DH;

    const char*  KB    = Kimg + (long)bh * NT * 4096;
    const char*  VB    = Vimg + (long)bh * NT * 4096;
    const float* biasB = bias + (bh >> 4) * S_LEN;

    // Q fragments (B operand), scale = (1/8)*log2(e) folded
    const float QS = 0.18033688011112042f;
    short8 bq[4];
    {
        const float* qp = Q + base + (long)(q0 + lq) * DH;
        #pragma unroll
        for (int s = 0; s < 4; ++s) {
            int d0 = s * 16 + hi * 8;
            f32x4 xx = *(const f32x4*)(qp + d0);
            f32x4 yy = *(const f32x4*)(qp + d0 + 4);
            union { short8 s8; unsigned u4[4]; } uu;
            uu.u4[0] = cvtpk_bf16(xx[0] * QS, xx[1] * QS);
            uu.u4[1] = cvtpk_bf16(xx[2] * QS, xx[3] * QS);
            uu.u4[2] = cvtpk_bf16(yy[0] * QS, yy[1] * QS);
            uu.u4[3] = cvtpk_bf16(yy[2] * QS, yy[3] * QS);
            bq[s] = uu.s8;
        }
    }

    f32x16 o0, o1;
    #pragma unroll
    for (int rr = 0; rr < 16; ++rr) { o0[rr] = 0.f; o1[rr] = 0.f; }
    float m_run = -1e30f, l_run = 0.f;

    short8 ka[4], kb_[4], va[4], vb_[4];
    f32x4  ba[4], bb[4];

    LOADB(ba, 0); LOADK(ka, 0); LOADV(va, 0);
    int t = 0;
    for (;;) {
        if (t + 1 < nkv) { LOADB(bb, t + 1); LOADK(kb_, t + 1); LOADV(vb_, t + 1); }
        COMPUTE(t, ka, va, ba);
        ++t; if (t >= nkv) break;
        if (t + 1 < nkv) { LOADB(ba, t + 1); LOADK(ka, t + 1); LOADV(va, t + 1); }
        COMPUTE(t, kb_, vb_, bb);
        ++t; if (t >= nkv) break;
    }

    // epilogue: out[q0+lq][d], d over o0 (0..31) / o1 (32..63)
    float invl = 1.0f / l_run;
    float* op = out + base + (long)(q0 + lq) * DH;
    #pragma unroll
    for (int g = 0; g < 4; ++g) {
        f32x4 w0, w1;
        #pragma unroll
        for (int i = 0; i < 4; ++i) {
            w0[i] = o0[g * 4 + i] * invl;
            w1[i] = o1[g * 4 + i] * invl;
        }
        *(f32x4*)(op + g * 8 + hi * 4)      = w0;
        *(f32x4*)(op + 32 + g * 8 + hi * 4) = w1;
    }
}

// ---------------------------------------------------------------------------
// Rows q < fz[b]: reference softmax degenerates to uniform over ALL 2048 keys
// (scores all exactly -1e9 in fp32) -> out = mean(V). Overwrite them.
// ---------------------------------------------------------------------------
__global__ void fixup_kernel(const int* __restrict__ fz, const float* __restrict__ meanv,
                             float* __restrict__ out)
{
    const int bh = blockIdx.x;
    const int b  = bh >> 4;
    const int n  = fz[b];
    if (n <= 0) return;
    __shared__ float mv[DH];
    if (threadIdx.x < DH) mv[threadIdx.x] = meanv[bh * DH + threadIdx.x];
    __syncthreads();
    float* op = out + (long)bh * S_LEN * DH;
    for (int i = threadIdx.x; i < n * DH; i += 256) op[i] = mv[i & 63];
}

extern "C" void kernel_launch(void* const* d_in, const int* in_sizes, int n_in,
                              void* d_out, int out_size, void* d_ws, size_t ws_size,
                              hipStream_t stream)
{
    const float* Q   = (const float*)d_in[0];
    const float* K   = (const float*)d_in[1];
    const float* V   = (const float*)d_in[2];
    const int*   pad = (const int*)d_in[3];
    float* out = (float*)d_out;

    int*   fz    = (int*)d_ws;                          // 2 ints
    float* meanv = (float*)((char*)d_ws + 256);         // 32*64 f32
    float* bias  = (float*)((char*)d_ws + 8448);        // 2*2048 f32
    char*  Kimg  = (char*)d_ws + 32768;                 // 8 MB
    char*  Vimg  = Kimg + (size_t)NBH * NT * 4096;      // 8 MB

    fz_kernel<<<dim3(2), dim3(256), 0, stream>>>(pad, fz);
    bias_kernel<<<dim3(2), dim3(1024), 0, stream>>>(pad, bias);
    prep_kernel<<<dim3(NT, NBH), dim3(256), 0, stream>>>(K, V, Kimg, Vimg);
    attn_fwd5<<<dim3(2048), dim3(64), 0, stream>>>(Q, Kimg, Vimg, bias, out);
    meanv_kernel<<<dim3(NBH), dim3(1024), 0, stream>>>(V, fz, meanv);
    fixup_kernel<<<dim3(NBH), dim3(256), 0, stream>>>(fz, meanv, out);
}

// Round 9
// 96.451 us; speedup vs baseline: 2.5800x; 1.2146x over previous
//
#include <hip/hip_runtime.h>
#include <hip/hip_bf16.h>

#define S_LEN 2048
#define DH    64
#define NBH   32          // B*H
#define KVT   32          // keys per tile
#define NT    64          // tiles per bh (S/KVT)

typedef __attribute__((ext_vector_type(8)))  short short8;
typedef __attribute__((ext_vector_type(4)))  float f32x4;
typedef __attribute__((ext_vector_type(16))) float f32x16;

static __device__ __forceinline__ unsigned cvtpk_bf16(float a, float b) {
    unsigned r;
    asm("v_cvt_pk_bf16_f32 %0, %1, %2" : "=v"(r) : "v"(a), "v"(b));
    return r;
}
// cross-half (lane ^ 32) reductions — __shfl_xor is proven on this target.
// (permlane32_swap with two identical "+v" operands gets register-coalesced
//  into a self-swap, dropping each lane's own half. Do not reintroduce.)
static __device__ __forceinline__ float xor32_max(float x) {
    return fmaxf(x, __shfl_xor(x, 32));
}
static __device__ __forceinline__ float xor32_add(float x) {
    return x + __shfl_xor(x, 32);
}

// ---------------------------------------------------------------------------
// prep: K,V fp32 -> bf16 fragment images (4 KB per 32-key tile).
// Kimg tile: [key 0..31][128B = 64 d bf16]   (MFMA A-operand rows)
// Vimg tile: [d 0..63][64B = 32 keys bf16]   (V^T, PV A-operand rows)
// grid = (NT, NBH), 256 threads.
// ---------------------------------------------------------------------------
__global__ __launch_bounds__(256)
void prep_kernel(const float* __restrict__ K, const float* __restrict__ V,
                 char* __restrict__ Kimg, char* __restrict__ Vimg)
{
    const int t = blockIdx.x, bh = blockIdx.y, tid = threadIdx.x;
    const long tileOff = ((long)bh * NT + t) * 4096;
    const float* kp = K + (long)bh * S_LEN * DH + t * KVT * DH;
    const float* vp = V + (long)bh * S_LEN * DH + t * KVT * DH;

    {   // K rows
        int key = tid >> 3, dc = tid & 7;
        f32x4 x = *(const f32x4*)(kp + key * 64 + dc * 8);
        f32x4 y = *(const f32x4*)(kp + key * 64 + dc * 8 + 4);
        uint4 w;
        w.x = cvtpk_bf16(x[0], x[1]);
        w.y = cvtpk_bf16(x[2], x[3]);
        w.z = cvtpk_bf16(y[0], y[1]);
        w.w = cvtpk_bf16(y[2], y[3]);
        *(uint4*)(Kimg + tileOff + key * 128 + dc * 16) = w;
    }
    {   // V^T rows (4x2 micro-transpose per thread)
        int vdg = tid & 15, vkq = tid >> 4;
        int d0 = vdg * 4, k0 = vkq * 2;
        f32x4 x0 = *(const f32x4*)(vp + k0 * 64 + d0);
        f32x4 x1 = *(const f32x4*)(vp + (k0 + 1) * 64 + d0);
        #pragma unroll
        for (int i = 0; i < 4; ++i)
            *(unsigned*)(Vimg + tileOff + (d0 + i) * 64 + k0 * 2) = cvtpk_bf16(x0[i], x1[i]);
    }
}

// ---------------------------------------------------------------------------
// fz[b] = first k with pad==0 (S if none)
// ---------------------------------------------------------------------------
__global__ void fz_kernel(const int* __restrict__ pad, int* __restrict__ fz)
{
    int b = blockIdx.x;
    __shared__ int red[256];
    int local = S_LEN;
    for (int k = threadIdx.x; k < S_LEN; k += 256)
        if (pad[b * S_LEN + k] == 0 && k < local) local = k;
    red[threadIdx.x] = local;
    __syncthreads();
    for (int s = 128; s > 0; s >>= 1) {
        if (threadIdx.x < s) red[threadIdx.x] = min(red[threadIdx.x], red[threadIdx.x + s]);
        __syncthreads();
    }
    if (threadIdx.x == 0) fz[b] = red[0];
}

// bias[b][k] = pad ? -1e30 : 0
__global__ __launch_bounds__(1024)
void bias_kernel(const int* __restrict__ pad, float* __restrict__ bias)
{
    int b = blockIdx.x;
    #pragma unroll
    for (int i = 0; i < 2; ++i) {
        int k = threadIdx.x + i * 1024;
        bias[b * S_LEN + k] = pad[b * S_LEN + k] ? -1e30f : 0.f;
    }
}

// ---------------------------------------------------------------------------
// meanv[bh][d] = mean over 2048 keys of V[bh,:,d] (only if fz[b] > 0).
// ---------------------------------------------------------------------------
__global__ __launch_bounds__(1024)
void meanv_kernel(const float* __restrict__ V, const int* __restrict__ fz,
                  float* __restrict__ meanv)
{
    const int bh = blockIdx.x;
    const int b  = bh >> 4;
    if (fz[b] <= 0) return;
    const int d4 = threadIdx.x & 15;
    const int kp = threadIdx.x >> 4;
    const float* vp = V + (long)bh * S_LEN * DH;
    f32x4 acc = (f32x4){0.f, 0.f, 0.f, 0.f};
    #pragma unroll 4
    for (int k = kp; k < S_LEN; k += 64)
        acc += *(const f32x4*)(vp + (long)k * DH + d4 * 4);
    __shared__ f32x4 red[64][16];
    red[kp][d4] = acc;
    __syncthreads();
    #pragma unroll
    for (int s = 32; s >= 1; s >>= 1) {
        if (kp < s) red[kp][d4] += red[kp + s][d4];
        __syncthreads();
    }
    if (kp == 0)
        *(f32x4*)(meanv + bh * DH + d4 * 4) = red[0][d4] * (1.0f / 2048.0f);
}

// ---------------------------------------------------------------------------
// attn v6: 1-wave blocks, zero LDS/barriers; round-6 mapping (empirically
// balanced: per-SIMD complementary (v, 63-v) pairs under observed placement);
// NEW: depth-2 register prefetch via 3 rotating banks (tile t computes while
// t+1 and t+2 loads are in flight -> ~800-900 cyc latency cover vs ~400).
// ---------------------------------------------------------------------------
#define LOADK(dst, tt) do { const char* _p = KB + (long)(tt) * 4096 + lq * 128 + hi * 16; \
    dst[0] = *(const short8*)(_p);       dst[1] = *(const short8*)(_p + 32);  \
    dst[2] = *(const short8*)(_p + 64);  dst[3] = *(const short8*)(_p + 96); } while (0)
#define LOADV(dst, tt) do { const char* _p = VB + (long)(tt) * 4096 + lq * 64 + hi * 16; \
    dst[0] = *(const short8*)(_p);        dst[1] = *(const short8*)(_p + 32); \
    dst[2] = *(const short8*)(_p + 2048); dst[3] = *(const short8*)(_p + 2048 + 32); } while (0)
#define LOADB(dst, tt) do { const float* _p = biasB + (tt) * 32 + hi * 4; \
    dst[0] = *(const f32x4*)(_p);      dst[1] = *(const f32x4*)(_p + 8); \
    dst[2] = *(const f32x4*)(_p + 16); dst[3] = *(const f32x4*)(_p + 24); } while (0)
#define LOADT(B, tt) do { LOADB(b##B, tt); LOADK(k##B, tt); LOADV(v##B, tt); } while (0)

#define COMPUTE(TT, K_, V_, B_) do {                                          \
    f32x16 s0;                                                                \
    _Pragma("unroll")                                                         \
    for (int g = 0; g < 4; ++g) {                                             \
        f32x4 pb4 = B_[g];                                                    \
        _Pragma("unroll")                                                     \
        for (int i = 0; i < 4; ++i) s0[g * 4 + i] = pb4[i];                   \
    }                                                                         \
    __builtin_amdgcn_s_setprio(1);                                            \
    s0 = __builtin_amdgcn_mfma_f32_32x32x16_bf16(K_[0], bq[0], s0, 0, 0, 0);  \
    s0 = __builtin_amdgcn_mfma_f32_32x32x16_bf16(K_[1], bq[1], s0, 0, 0, 0);  \
    s0 = __builtin_amdgcn_mfma_f32_32x32x16_bf16(K_[2], bq[2], s0, 0, 0, 0);  \
    s0 = __builtin_amdgcn_mfma_f32_32x32x16_bf16(K_[3], bq[3], s0, 0, 0, 0);  \
    __builtin_amdgcn_s_setprio(0);                                            \
    if ((TT) == nkv - 1) {                                                    \
        _Pragma("unroll")                                                     \
        for (int rr = 0; rr < 16; ++rr) {                                     \
            int key_r = (rr & 3) + 8 * (rr >> 2) + 4 * hi;                    \
            if (key_r > lq) s0[rr] = -1e30f;                                  \
        }                                                                     \
    }                                                                         \
    float bm = s0[0];                                                         \
    _Pragma("unroll")                                                         \
    for (int rr = 1; rr < 16; ++rr) bm = fmaxf(bm, s0[rr]);                   \
    bm = xor32_max(bm);                                                       \
    if (__any(bm > m_run + 8.0f)) {                                           \
        float mnew = fmaxf(m_run, bm);                                        \
        float c = exp2f(m_run - mnew);                                        \
        m_run = mnew; l_run *= c;                                             \
        _Pragma("unroll")                                                     \
        for (int rr = 0; rr < 16; ++rr) { o0[rr] *= c; o1[rr] *= c; }         \
    }                                                                         \
    float rs = 0.f;                                                           \
    _Pragma("unroll")                                                         \
    for (int rr = 0; rr < 16; ++rr) {                                         \
        float p = exp2f(s0[rr] - m_run);                                      \
        s0[rr] = p; rs += p;                                                  \
    }                                                                         \
    l_run += xor32_add(rs);                                                   \
    short8 pfr0, pfr1;                                                        \
    {                                                                         \
        unsigned a0 = cvtpk_bf16(s0[0], s0[1]), b0 = cvtpk_bf16(s0[4], s0[5]);\
        asm("v_permlane32_swap_b32 %0, %1" : "+v"(a0), "+v"(b0));             \
        unsigned a1 = cvtpk_bf16(s0[2], s0[3]), b1 = cvtpk_bf16(s0[6], s0[7]);\
        asm("v_permlane32_swap_b32 %0, %1" : "+v"(a1), "+v"(b1));             \
        union { short8 s8; unsigned u[4]; } u;                                \
        u.u[0] = a0; u.u[1] = a1; u.u[2] = b0; u.u[3] = b1;                   \
        pfr0 = u.s8;                                                          \
    }                                                                         \
    {                                                                         \
        unsigned a0 = cvtpk_bf16(s0[8], s0[9]),  b0 = cvtpk_bf16(s0[12], s0[13]); \
        asm("v_permlane32_swap_b32 %0, %1" : "+v"(a0), "+v"(b0));             \
        unsigned a1 = cvtpk_bf16(s0[10], s0[11]), b1 = cvtpk_bf16(s0[14], s0[15]); \
        asm("v_permlane32_swap_b32 %0, %1" : "+v"(a1), "+v"(b1));             \
        union { short8 s8; unsigned u[4]; } u;                                \
        u.u[0] = a0; u.u[1] = a1; u.u[2] = b0; u.u[3] = b1;                   \
        pfr1 = u.s8;                                                          \
    }                                                                         \
    __builtin_amdgcn_s_setprio(1);                                            \
    o0 = __builtin_amdgcn_mfma_f32_32x32x16_bf16(V_[0], pfr0, o0, 0, 0, 0);   \
    o0 = __builtin_amdgcn_mfma_f32_32x32x16_bf16(V_[1], pfr1, o0, 0, 0, 0);   \
    o1 = __builtin_amdgcn_mfma_f32_32x32x16_bf16(V_[2], pfr0, o1, 0, 0, 0);   \
    o1 = __builtin_amdgcn_mfma_f32_32x32x16_bf16(V_[3], pfr1, o1, 0, 0, 0);   \
    __builtin_amdgcn_s_setprio(0);                                            \
} while (0)

__global__ __launch_bounds__(64, 2)
void attn_fwd6(const float* __restrict__ Q, const char* __restrict__ Kimg,
               const char* __restrict__ Vimg, const float* __restrict__ bias,
               float* __restrict__ out)
{
    const int lane = threadIdx.x;
    const int lq = lane & 31, hi = lane >> 5;

    // round-6 mapping (verbatim): per-SIMD complementary pairs
    const int gid = blockIdx.x;
    const int j = gid >> 8, r = gid & 255;
    const int bh = r >> 3;
    const int v = (j & 3) * 8 + (r & 7);
    const int bx = (j >> 2) ? 63 - v : v;
    const int q0 = bx * 32;
    const int nkv = bx + 1;
    const long base = (long)bh * S_LEN * DH;

    const char*  KB    = Kimg + (long)bh * NT * 4096;
    const char*  VB    = Vimg + (long)bh * NT * 4096;
    const float* biasB = bias + (bh >> 4) * S_LEN;

    // Q fragments (B operand), scale = (1/8)*log2(e) folded
    const float QS = 0.18033688011112042f;
    short8 bq[4];
    {
        const float* qp = Q + base + (long)(q0 + lq) * DH;
        #pragma unroll
        for (int s = 0; s < 4; ++s) {
            int d0 = s * 16 + hi * 8;
            f32x4 x = *(const f32x4*)(qp + d0);
            f32x4 y = *(const f32x4*)(qp + d0 + 4);
            union { short8 s8; unsigned u[4]; } u;
            u.u[0] = cvtpk_bf16(x[0] * QS, x[1] * QS);
            u.u[1] = cvtpk_bf16(x[2] * QS, x[3] * QS);
            u.u[2] = cvtpk_bf16(y[0] * QS, y[1] * QS);
            u.u[3] = cvtpk_bf16(y[2] * QS, y[3] * QS);
            bq[s] = u.s8;
        }
    }

    f32x16 o0, o1;
    #pragma unroll
    for (int rr = 0; rr < 16; ++rr) { o0[rr] = 0.f; o1[rr] = 0.f; }
    float m_run = -1e30f, l_run = 0.f;

    // three prefetch banks (static indices only — rule #20)
    short8 kA[4], kB_[4], kC[4], vA[4], vB_[4], vC[4];
    f32x4  bA[4], bB_[4], bC[4];

    LOADB(bA, 0);  LOADK(kA, 0);  LOADV(vA, 0);
    if (nkv > 1) { LOADB(bB_, 1); LOADK(kB_, 1); LOADV(vB_, 1); }

    int t = 0;
    for (;;) {
        if (t + 2 < nkv) { LOADB(bC, t + 2);  LOADK(kC, t + 2);  LOADV(vC, t + 2); }
        COMPUTE(t, kA, vA, bA);
        ++t; if (t >= nkv) break;
        if (t + 2 < nkv) { LOADB(bA, t + 2);  LOADK(kA, t + 2);  LOADV(vA, t + 2); }
        COMPUTE(t, kB_, vB_, bB_);
        ++t; if (t >= nkv) break;
        if (t + 2 < nkv) { LOADB(bB_, t + 2); LOADK(kB_, t + 2); LOADV(vB_, t + 2); }
        COMPUTE(t, kC, vC, bC);
        ++t; if (t >= nkv) break;
    }

    // epilogue: out[q0+lq][d], d over o0 (0..31) / o1 (32..63)
    float invl = 1.0f / l_run;
    float* op = out + base + (long)(q0 + lq) * DH;
    #pragma unroll
    for (int g = 0; g < 4; ++g) {
        f32x4 w0, w1;
        #pragma unroll
        for (int i = 0; i < 4; ++i) {
            w0[i] = o0[g * 4 + i] * invl;
            w1[i] = o1[g * 4 + i] * invl;
        }
        *(f32x4*)(op + g * 8 + hi * 4)      = w0;
        *(f32x4*)(op + 32 + g * 8 + hi * 4) = w1;
    }
}

// ---------------------------------------------------------------------------
// Rows q < fz[b]: reference softmax degenerates to uniform over ALL 2048 keys
// (scores all exactly -1e9 in fp32) -> out = mean(V). Overwrite them.
// ---------------------------------------------------------------------------
__global__ void fixup_kernel(const int* __restrict__ fz, const float* __restrict__ meanv,
                             float* __restrict__ out)
{
    const int bh = blockIdx.x;
    const int b  = bh >> 4;
    const int n  = fz[b];
    if (n <= 0) return;
    __shared__ float mv[DH];
    if (threadIdx.x < DH) mv[threadIdx.x] = meanv[bh * DH + threadIdx.x];
    __syncthreads();
    float* op = out + (long)bh * S_LEN * DH;
    for (int i = threadIdx.x; i < n * DH; i += 256) op[i] = mv[i & 63];
}

extern "C" void kernel_launch(void* const* d_in, const int* in_sizes, int n_in,
                              void* d_out, int out_size, void* d_ws, size_t ws_size,
                              hipStream_t stream)
{
    const float* Q   = (const float*)d_in[0];
    const float* K   = (const float*)d_in[1];
    const float* V   = (const float*)d_in[2];
    const int*   pad = (const int*)d_in[3];
    float* out = (float*)d_out;

    int*   fz    = (int*)d_ws;                          // 2 ints
    float* meanv = (float*)((char*)d_ws + 256);         // 32*64 f32
    float* bias  = (float*)((char*)d_ws + 8448);        // 2*2048 f32
    char*  Kimg  = (char*)d_ws + 32768;                 // 8 MB
    char*  Vimg  = Kimg + (size_t)NBH * NT * 4096;      // 8 MB

    fz_kernel<<<dim3(2), dim3(256), 0, stream>>>(pad, fz);
    bias_kernel<<<dim3(2), dim3(1024), 0, stream>>>(pad, bias);
    prep_kernel<<<dim3(NT, NBH), dim3(256), 0, stream>>>(K, V, Kimg, Vimg);
    attn_fwd6<<<dim3(2048), dim3(64), 0, stream>>>(Q, Kimg, Vimg, bias, out);
    meanv_kernel<<<dim3(NBH), dim3(1024), 0, stream>>>(V, fz, meanv);
    fixup_kernel<<<dim3(NBH), dim3(256), 0, stream>>>(fz, meanv, out);
}

// Round 10
// 94.106 us; speedup vs baseline: 2.6443x; 1.0249x over previous
//
#include <hip/hip_runtime.h>
#include <hip/hip_bf16.h>

#define S_LEN 2048
#define DH    64
#define NBH   32          // B*H
#define KVT   32          // keys per tile
#define NT    64          // tiles per bh (S/KVT)

typedef __attribute__((ext_vector_type(8)))  short short8;
typedef __attribute__((ext_vector_type(4)))  float f32x4;
typedef __attribute__((ext_vector_type(16))) float f32x16;

static __device__ __forceinline__ unsigned cvtpk_bf16(float a, float b) {
    unsigned r;
    asm("v_cvt_pk_bf16_f32 %0, %1, %2" : "=v"(r) : "v"(a), "v"(b));
    return r;
}
// cross-half (lane ^ 32) reductions — __shfl_xor is proven on this target.
// (permlane32_swap with two identical "+v" operands gets register-coalesced
//  into a self-swap, dropping each lane's own half. Do not reintroduce.)
static __device__ __forceinline__ float xor32_max(float x) {
    return fmaxf(x, __shfl_xor(x, 32));
}
static __device__ __forceinline__ float xor32_add(float x) {
    return x + __shfl_xor(x, 32);
}

// ---------------------------------------------------------------------------
// prep: K,V fp32 -> bf16 fragment images (4 KB per 32-key tile).
// Kimg tile: [key 0..31][128B = 64 d bf16]   (MFMA A-operand rows)
// Vimg tile: [d 0..63][64B = 32 keys bf16]   (V^T, PV A-operand rows)
// grid = (NT, NBH), 256 threads.
// ---------------------------------------------------------------------------
__global__ __launch_bounds__(256)
void prep_kernel(const float* __restrict__ K, const float* __restrict__ V,
                 char* __restrict__ Kimg, char* __restrict__ Vimg)
{
    const int t = blockIdx.x, bh = blockIdx.y, tid = threadIdx.x;
    const long tileOff = ((long)bh * NT + t) * 4096;
    const float* kp = K + (long)bh * S_LEN * DH + t * KVT * DH;
    const float* vp = V + (long)bh * S_LEN * DH + t * KVT * DH;

    {   // K rows
        int key = tid >> 3, dc = tid & 7;
        f32x4 x = *(const f32x4*)(kp + key * 64 + dc * 8);
        f32x4 y = *(const f32x4*)(kp + key * 64 + dc * 8 + 4);
        uint4 w;
        w.x = cvtpk_bf16(x[0], x[1]);
        w.y = cvtpk_bf16(x[2], x[3]);
        w.z = cvtpk_bf16(y[0], y[1]);
        w.w = cvtpk_bf16(y[2], y[3]);
        *(uint4*)(Kimg + tileOff + key * 128 + dc * 16) = w;
    }
    {   // V^T rows (4x2 micro-transpose per thread)
        int vdg = tid & 15, vkq = tid >> 4;
        int d0 = vdg * 4, k0 = vkq * 2;
        f32x4 x0 = *(const f32x4*)(vp + k0 * 64 + d0);
        f32x4 x1 = *(const f32x4*)(vp + (k0 + 1) * 64 + d0);
        #pragma unroll
        for (int i = 0; i < 4; ++i)
            *(unsigned*)(Vimg + tileOff + (d0 + i) * 64 + k0 * 2) = cvtpk_bf16(x0[i], x1[i]);
    }
}

// ---------------------------------------------------------------------------
// fz[b] = first k with pad==0 (S if none)
// ---------------------------------------------------------------------------
__global__ void fz_kernel(const int* __restrict__ pad, int* __restrict__ fz)
{
    int b = blockIdx.x;
    __shared__ int red[256];
    int local = S_LEN;
    for (int k = threadIdx.x; k < S_LEN; k += 256)
        if (pad[b * S_LEN + k] == 0 && k < local) local = k;
    red[threadIdx.x] = local;
    __syncthreads();
    for (int s = 128; s > 0; s >>= 1) {
        if (threadIdx.x < s) red[threadIdx.x] = min(red[threadIdx.x], red[threadIdx.x + s]);
        __syncthreads();
    }
    if (threadIdx.x == 0) fz[b] = red[0];
}

// bias[b][k] = pad ? -1e30 : 0
__global__ __launch_bounds__(1024)
void bias_kernel(const int* __restrict__ pad, float* __restrict__ bias)
{
    int b = blockIdx.x;
    #pragma unroll
    for (int i = 0; i < 2; ++i) {
        int k = threadIdx.x + i * 1024;
        bias[b * S_LEN + k] = pad[b * S_LEN + k] ? -1e30f : 0.f;
    }
}

// ---------------------------------------------------------------------------
// meanv[bh][d] = mean over 2048 keys of V[bh,:,d] (only if fz[b] > 0).
// ---------------------------------------------------------------------------
__global__ __launch_bounds__(1024)
void meanv_kernel(const float* __restrict__ V, const int* __restrict__ fz,
                  float* __restrict__ meanv)
{
    const int bh = blockIdx.x;
    const int b  = bh >> 4;
    if (fz[b] <= 0) return;
    const int d4 = threadIdx.x & 15;
    const int kp = threadIdx.x >> 4;
    const float* vp = V + (long)bh * S_LEN * DH;
    f32x4 acc = (f32x4){0.f, 0.f, 0.f, 0.f};
    #pragma unroll 4
    for (int k = kp; k < S_LEN; k += 64)
        acc += *(const f32x4*)(vp + (long)k * DH + d4 * 4);
    __shared__ f32x4 red[64][16];
    red[kp][d4] = acc;
    __syncthreads();
    #pragma unroll
    for (int s = 32; s >= 1; s >>= 1) {
        if (kp < s) red[kp][d4] += red[kp + s][d4];
        __syncthreads();
    }
    if (kp == 0)
        *(f32x4*)(meanv + bh * DH + d4 * 4) = red[0][d4] * (1.0f / 2048.0f);
}

// ---------------------------------------------------------------------------
// attn v7: 1-wave blocks, zero LDS/barriers, depth-2 register prefetch.
// Mapping combines r8's PROVEN XCD locality with r6's PROVEN SIMD balance,
// using the placement model confirmed by r8's FETCH drop:
//   XCD = gid&7, CU = (gid>>3)&31, SIMD = (gid>>8)&3, slot = gid>>10.
//   bh = (gid&7) + 8*(CU&3)     -> each XCD class touches 4 bh (2 MB, L2-fit)
//   e  = (CU>>2)*4 + SIMD       -> 0..31
//   bx = slot ? 63-e : e        -> same-SIMD pair = (e, 63-e): 65 tiles const,
//                                  same bh on both waves (L1 reuse).
// Pure heuristic: any placement still gives full coverage (bijection, G16).
// ---------------------------------------------------------------------------
#define LOADK(dst, tt) do { const char* _p = KB + (long)(tt) * 4096 + lq * 128 + hi * 16; \
    dst[0] = *(const short8*)(_p);       dst[1] = *(const short8*)(_p + 32);  \
    dst[2] = *(const short8*)(_p + 64);  dst[3] = *(const short8*)(_p + 96); } while (0)
#define LOADV(dst, tt) do { const char* _p = VB + (long)(tt) * 4096 + lq * 64 + hi * 16; \
    dst[0] = *(const short8*)(_p);        dst[1] = *(const short8*)(_p + 32); \
    dst[2] = *(const short8*)(_p + 2048); dst[3] = *(const short8*)(_p + 2048 + 32); } while (0)
#define LOADB(dst, tt) do { const float* _p = biasB + (tt) * 32 + hi * 4; \
    dst[0] = *(const f32x4*)(_p);      dst[1] = *(const f32x4*)(_p + 8); \
    dst[2] = *(const f32x4*)(_p + 16); dst[3] = *(const f32x4*)(_p + 24); } while (0)

#define COMPUTE(TT, K_, V_, B_) do {                                          \
    f32x16 s0;                                                                \
    _Pragma("unroll")                                                         \
    for (int g = 0; g < 4; ++g) {                                             \
        f32x4 pb4 = B_[g];                                                    \
        _Pragma("unroll")                                                     \
        for (int i = 0; i < 4; ++i) s0[g * 4 + i] = pb4[i];                   \
    }                                                                         \
    __builtin_amdgcn_s_setprio(1);                                            \
    s0 = __builtin_amdgcn_mfma_f32_32x32x16_bf16(K_[0], bq[0], s0, 0, 0, 0);  \
    s0 = __builtin_amdgcn_mfma_f32_32x32x16_bf16(K_[1], bq[1], s0, 0, 0, 0);  \
    s0 = __builtin_amdgcn_mfma_f32_32x32x16_bf16(K_[2], bq[2], s0, 0, 0, 0);  \
    s0 = __builtin_amdgcn_mfma_f32_32x32x16_bf16(K_[3], bq[3], s0, 0, 0, 0);  \
    __builtin_amdgcn_s_setprio(0);                                            \
    if ((TT) == nkv - 1) {                                                    \
        _Pragma("unroll")                                                     \
        for (int rr = 0; rr < 16; ++rr) {                                     \
            int key_r = (rr & 3) + 8 * (rr >> 2) + 4 * hi;                    \
            if (key_r > lq) s0[rr] = -1e30f;                                  \
        }                                                                     \
    }                                                                         \
    float bm = s0[0];                                                         \
    _Pragma("unroll")                                                         \
    for (int rr = 1; rr < 16; ++rr) bm = fmaxf(bm, s0[rr]);                   \
    bm = xor32_max(bm);                                                       \
    if (__any(bm > m_run + 8.0f)) {                                           \
        float mnew = fmaxf(m_run, bm);                                        \
        float c = exp2f(m_run - mnew);                                        \
        m_run = mnew; l_run *= c;                                             \
        _Pragma("unroll")                                                     \
        for (int rr = 0; rr < 16; ++rr) { o0[rr] *= c; o1[rr] *= c; }         \
    }                                                                         \
    float rs = 0.f;                                                           \
    _Pragma("unroll")                                                         \
    for (int rr = 0; rr < 16; ++rr) {                                         \
        float p = exp2f(s0[rr] - m_run);                                      \
        s0[rr] = p; rs += p;                                                  \
    }                                                                         \
    l_run += xor32_add(rs);                                                   \
    short8 pfr0, pfr1;                                                        \
    {                                                                         \
        unsigned a0 = cvtpk_bf16(s0[0], s0[1]), b0 = cvtpk_bf16(s0[4], s0[5]);\
        asm("v_permlane32_swap_b32 %0, %1" : "+v"(a0), "+v"(b0));             \
        unsigned a1 = cvtpk_bf16(s0[2], s0[3]), b1 = cvtpk_bf16(s0[6], s0[7]);\
        asm("v_permlane32_swap_b32 %0, %1" : "+v"(a1), "+v"(b1));             \
        union { short8 s8; unsigned u[4]; } u;                                \
        u.u[0] = a0; u.u[1] = a1; u.u[2] = b0; u.u[3] = b1;                   \
        pfr0 = u.s8;                                                          \
    }                                                                         \
    {                                                                         \
        unsigned a0 = cvtpk_bf16(s0[8], s0[9]),  b0 = cvtpk_bf16(s0[12], s0[13]); \
        asm("v_permlane32_swap_b32 %0, %1" : "+v"(a0), "+v"(b0));             \
        unsigned a1 = cvtpk_bf16(s0[10], s0[11]), b1 = cvtpk_bf16(s0[14], s0[15]); \
        asm("v_permlane32_swap_b32 %0, %1" : "+v"(a1), "+v"(b1));             \
        union { short8 s8; unsigned u[4]; } u;                                \
        u.u[0] = a0; u.u[1] = a1; u.u[2] = b0; u.u[3] = b1;                   \
        pfr1 = u.s8;                                                          \
    }                                                                         \
    __builtin_amdgcn_s_setprio(1);                                            \
    o0 = __builtin_amdgcn_mfma_f32_32x32x16_bf16(V_[0], pfr0, o0, 0, 0, 0);   \
    o0 = __builtin_amdgcn_mfma_f32_32x32x16_bf16(V_[1], pfr1, o0, 0, 0, 0);   \
    o1 = __builtin_amdgcn_mfma_f32_32x32x16_bf16(V_[2], pfr0, o1, 0, 0, 0);   \
    o1 = __builtin_amdgcn_mfma_f32_32x32x16_bf16(V_[3], pfr1, o1, 0, 0, 0);   \
    __builtin_amdgcn_s_setprio(0);                                            \
} while (0)

__global__ __launch_bounds__(64, 2)
void attn_fwd7(const float* __restrict__ Q, const char* __restrict__ Kimg,
               const char* __restrict__ Vimg, const float* __restrict__ bias,
               float* __restrict__ out)
{
    const int lane = threadIdx.x;
    const int lq = lane & 31, hi = lane >> 5;

    // locality+balance mapping (see header comment)
    const int gid = blockIdx.x;
    const int x   = gid & 7;
    const int c   = (gid >> 3) & 31;
    const int m   = (gid >> 8) & 3;
    const int s   = gid >> 10;
    const int bh  = x + 8 * (c & 3);
    const int e   = ((c >> 2) << 2) | m;     // 0..31
    const int bx  = s ? 63 - e : e;
    const int q0  = bx * 32;
    const int nkv = bx + 1;
    const long base = (long)bh * S_LEN * DH;

    const char*  KB    = Kimg + (long)bh * NT * 4096;
    const char*  VB    = Vimg + (long)bh * NT * 4096;
    const float* biasB = bias + (bh >> 4) * S_LEN;

    // Q fragments (B operand), scale = (1/8)*log2(e) folded
    const float QS = 0.18033688011112042f;
    short8 bq[4];
    {
        const float* qp = Q + base + (long)(q0 + lq) * DH;
        #pragma unroll
        for (int ss = 0; ss < 4; ++ss) {
            int d0 = ss * 16 + hi * 8;
            f32x4 xx = *(const f32x4*)(qp + d0);
            f32x4 yy = *(const f32x4*)(qp + d0 + 4);
            union { short8 s8; unsigned u4[4]; } uu;
            uu.u4[0] = cvtpk_bf16(xx[0] * QS, xx[1] * QS);
            uu.u4[1] = cvtpk_bf16(xx[2] * QS, xx[3] * QS);
            uu.u4[2] = cvtpk_bf16(yy[0] * QS, yy[1] * QS);
            uu.u4[3] = cvtpk_bf16(yy[2] * QS, yy[3] * QS);
            bq[ss] = uu.s8;
        }
    }

    f32x16 o0, o1;
    #pragma unroll
    for (int rr = 0; rr < 16; ++rr) { o0[rr] = 0.f; o1[rr] = 0.f; }
    float m_run = -1e30f, l_run = 0.f;

    // three prefetch banks (static indices only — rule #20)
    short8 kA[4], kB_[4], kC[4], vA[4], vB_[4], vC[4];
    f32x4  bA[4], bB_[4], bC[4];

    LOADB(bA, 0);  LOADK(kA, 0);  LOADV(vA, 0);
    if (nkv > 1) { LOADB(bB_, 1); LOADK(kB_, 1); LOADV(vB_, 1); }

    int t = 0;
    for (;;) {
        if (t + 2 < nkv) { LOADB(bC, t + 2);  LOADK(kC, t + 2);  LOADV(vC, t + 2); }
        COMPUTE(t, kA, vA, bA);
        ++t; if (t >= nkv) break;
        if (t + 2 < nkv) { LOADB(bA, t + 2);  LOADK(kA, t + 2);  LOADV(vA, t + 2); }
        COMPUTE(t, kB_, vB_, bB_);
        ++t; if (t >= nkv) break;
        if (t + 2 < nkv) { LOADB(bB_, t + 2); LOADK(kB_, t + 2); LOADV(vB_, t + 2); }
        COMPUTE(t, kC, vC, bC);
        ++t; if (t >= nkv) break;
    }

    // epilogue: out[q0+lq][d], d over o0 (0..31) / o1 (32..63)
    float invl = 1.0f / l_run;
    float* op = out + base + (long)(q0 + lq) * DH;
    #pragma unroll
    for (int g = 0; g < 4; ++g) {
        f32x4 w0, w1;
        #pragma unroll
        for (int i = 0; i < 4; ++i) {
            w0[i] = o0[g * 4 + i] * invl;
            w1[i] = o1[g * 4 + i] * invl;
        }
        *(f32x4*)(op + g * 8 + hi * 4)      = w0;
        *(f32x4*)(op + 32 + g * 8 + hi * 4) = w1;
    }
}

// ---------------------------------------------------------------------------
// Rows q < fz[b]: reference softmax degenerates to uniform over ALL 2048 keys
// (scores all exactly -1e9 in fp32) -> out = mean(V). Overwrite them.
// ---------------------------------------------------------------------------
__global__ void fixup_kernel(const int* __restrict__ fz, const float* __restrict__ meanv,
                             float* __restrict__ out)
{
    const int bh = blockIdx.x;
    const int b  = bh >> 4;
    const int n  = fz[b];
    if (n <= 0) return;
    __shared__ float mv[DH];
    if (threadIdx.x < DH) mv[threadIdx.x] = meanv[bh * DH + threadIdx.x];
    __syncthreads();
    float* op = out + (long)bh * S_LEN * DH;
    for (int i = threadIdx.x; i < n * DH; i += 256) op[i] = mv[i & 63];
}

extern "C" void kernel_launch(void* const* d_in, const int* in_sizes, int n_in,
                              void* d_out, int out_size, void* d_ws, size_t ws_size,
                              hipStream_t stream)
{
    const float* Q   = (const float*)d_in[0];
    const float* K   = (const float*)d_in[1];
    const float* V   = (const float*)d_in[2];
    const int*   pad = (const int*)d_in[3];
    float* out = (float*)d_out;

    int*   fz    = (int*)d_ws;                          // 2 ints
    float* meanv = (float*)((char*)d_ws + 256);         // 32*64 f32
    float* bias  = (float*)((char*)d_ws + 8448);        // 2*2048 f32
    char*  Kimg  = (char*)d_ws + 32768;                 // 8 MB
    char*  Vimg  = Kimg + (size_t)NBH * NT * 4096;      // 8 MB

    fz_kernel<<<dim3(2), dim3(256), 0, stream>>>(pad, fz);
    bias_kernel<<<dim3(2), dim3(1024), 0, stream>>>(pad, bias);
    prep_kernel<<<dim3(NT, NBH), dim3(256), 0, stream>>>(K, V, Kimg, Vimg);
    attn_fwd7<<<dim3(2048), dim3(64), 0, stream>>>(Q, Kimg, Vimg, bias, out);
    meanv_kernel<<<dim3(NBH), dim3(1024), 0, stream>>>(V, fz, meanv);
    fixup_kernel<<<dim3(NBH), dim3(256), 0, stream>>>(fz, meanv, out);
}